// Round 9
// baseline (118.172 us; speedup 1.0000x reference)
//
#include <hip/hip_runtime.h>
#include <math.h>

#define TB 8      // batch
#define TT 128    // tokens
#define TD 768    // dim
#define TH 768    // hidden
#define LN_EPS 1e-5f

// 4-K-row FMA body: weight rows in WV[0..3] (4 cols/lane) against
// LDS-broadcast activations st[b][ROW..ROW+3].
#define BODY4(WV, ROW)                                                \
  {                                                                   \
    float4 xq[8];                                                     \
    _Pragma("unroll") for (int b = 0; b < 8; ++b)                     \
        xq[b] = *(const float4*)&st[b][(ROW)];                        \
    _Pragma("unroll") for (int k = 0; k < 4; ++k) {                   \
      _Pragma("unroll") for (int b = 0; b < 8; ++b) {                 \
        const float xv = ((const float*)&xq[b])[k];                   \
        acc[b][0] = fmaf(xv, (WV)[k].x, acc[b][0]);                   \
        acc[b][1] = fmaf(xv, (WV)[k].y, acc[b][1]);                   \
        acc[b][2] = fmaf(xv, (WV)[k].z, acc[b][2]);                   \
        acc[b][3] = fmaf(xv, (WV)[k].w, acc[b][3]);                   \
      }                                                               \
    }                                                                 \
  }

// K-row mapping (round 9): half-wave hw owns rows {hw*4 + 32g : g=0..23},
// 4 consecutive rows per group. A wave's two halves are 4 rows apart, so
// each wave-instruction covers 8 consecutive weight rows, and the block
// walks one compact 32-row (96 KB) slab per group, front to back —
// clustering DRAM-page touches. Reduction algebra unchanged (row-sum is
// order-invariant): shfl_xor(32) merges the two halves, red[] merges waves.

// ---------------------------------------------------------------------------
// FF1 with fused LayerNorm. Block = (token t, 128-col slice of H), 256 thr.
// ---------------------------------------------------------------------------
__global__ __launch_bounds__(256) void ff1_kernel(
    const float* __restrict__ x,      // [B][T][D]
    const float* __restrict__ gamma,  // [T][D]
    const float* __restrict__ beta,   // [T][D]
    const float* __restrict__ W1,     // [T][D][H]
    const float* __restrict__ b1,     // [T][H]
    float* __restrict__ hbuf) {       // [T][B][H]
  __shared__ float st[TB][TD];        // 24 KB normalized activations
  __shared__ float red[4][8][128];    // 16 KB partial sums
  const int tid = threadIdx.x;
  const int w = tid >> 6, lane = tid & 63;
  const int half = lane >> 5, l32 = lane & 31;
  const int t = blockIdx.x / 6, slice = blockIdx.x % 6;
  const int cg = l32 * 4;
  const int c = slice * 128 + cg;
  const int rbase = w * 8 + half * 4;   // rows rbase + 32g, g = 0..23

  const float* wp1 = W1 + ((size_t)t * TD + rbase) * TH + c;

  // ---- LN x-loads first (needed soonest), then first-group weight prefetch
  const int bb = w * 2 + half;
  const float* xr = x + ((size_t)bb * TT + t) * TD;
  float4 v[6];
#pragma unroll
  for (int i = 0; i < 6; ++i)
    v[i] = *(const float4*)(xr + i * 128 + l32 * 4);

  float4 pA[4], pB[4];
#pragma unroll
  for (int k = 0; k < 4; ++k) pA[k] = *(const float4*)(wp1 + k * TH);
#pragma unroll
  for (int k = 0; k < 4; ++k) pB[k] = *(const float4*)(wp1 + (32 + k) * TH);

  {  // ---- fused LN for batch row bb ----
    float s = 0.f, ss = 0.f;
#pragma unroll
    for (int i = 0; i < 6; ++i) {
      s += v[i].x + v[i].y + v[i].z + v[i].w;
      ss += v[i].x * v[i].x + v[i].y * v[i].y + v[i].z * v[i].z +
            v[i].w * v[i].w;
    }
#pragma unroll
    for (int off = 16; off; off >>= 1) {  // reduce within the 32-lane half
      s  += __shfl_xor(s, off, 64);
      ss += __shfl_xor(ss, off, 64);
    }
    const float mu   = s * (1.f / TD);
    const float var  = ss * (1.f / TD) - mu * mu;
    const float rstd = rsqrtf(var + LN_EPS);
#pragma unroll
    for (int i = 0; i < 6; ++i) {
      const int d = i * 128 + l32 * 4;
      const float4 g  = *(const float4*)(gamma + (size_t)t * TD + d);
      const float4 be = *(const float4*)(beta  + (size_t)t * TD + d);
      float4 o;
      o.x = (v[i].x - mu) * rstd * g.x + be.x;
      o.y = (v[i].y - mu) * rstd * g.y + be.y;
      o.z = (v[i].z - mu) * rstd * g.z + be.z;
      o.w = (v[i].w - mu) * rstd * g.w + be.w;
      *(float4*)&st[bb][d] = o;
    }
  }
  __syncthreads();

  float acc[8][4];
#pragma unroll
  for (int b = 0; b < 8; ++b)
#pragma unroll
    for (int j = 0; j < 4; ++j) acc[b][j] = 0.f;

  BODY4(pA, rbase);
  BODY4(pB, rbase + 32);
  {
    const float* wp = wp1 + (size_t)64 * TH;
#pragma unroll 2
    for (int g = 2; g < 24; ++g) {
      float4 wv[4];
#pragma unroll
      for (int k = 0; k < 4; ++k) wv[k] = *(const float4*)(wp + k * TH);
      wp += 32 * TH;
      BODY4(wv, rbase + 32 * g);
    }
  }

#pragma unroll
  for (int b = 0; b < 8; ++b)
#pragma unroll
    for (int j = 0; j < 4; ++j)
      acc[b][j] += __shfl_xor(acc[b][j], 32, 64);
  if (lane < 32) {
#pragma unroll
    for (int b = 0; b < 8; ++b)
      *(float4*)&red[w][b][cg] =
          make_float4(acc[b][0], acc[b][1], acc[b][2], acc[b][3]);
  }
  __syncthreads();

  {  // epilogue: bias + GELU, thread -> (batch row, 4-col group)
    const int b = tid >> 5;
    const int colq = (tid & 31) * 4;
    const int cc = slice * 128 + colq;
    const float4 bias = *(const float4*)(b1 + (size_t)t * TH + cc);
    float4 o;
    float* po = (float*)&o;
    const float* pb = (const float*)&bias;
#pragma unroll
    for (int k = 0; k < 4; ++k) {
      float vv = red[0][b][colq + k] + red[1][b][colq + k] +
                 red[2][b][colq + k] + red[3][b][colq + k] + pb[k];
      po[k] = 0.5f * vv * (1.f + erff(vv * 0.7071067811865476f));
    }
    *(float4*)(hbuf + ((size_t)t * TB + b) * TH + cc) = o;
  }
}

// ---------------------------------------------------------------------------
// FF2: out = h @ W2 + b2 + x. Same structure and row mapping.
// ---------------------------------------------------------------------------
__global__ __launch_bounds__(256) void ff2_kernel(
    const float* __restrict__ hbuf, // [T][B][H]
    const float* __restrict__ W2,   // [T][H][D]
    const float* __restrict__ b2,   // [T][D]
    const float* __restrict__ x,    // [B][T][D]
    float* __restrict__ out) {      // [B][T][D]
  __shared__ float st[TB][TH];
  __shared__ float red[4][8][128];
  const int tid = threadIdx.x;
  const int w = tid >> 6, lane = tid & 63;
  const int half = lane >> 5, l32 = lane & 31;
  const int t = blockIdx.x / 6, slice = blockIdx.x % 6;
  const int cg = l32 * 4;
  const int c = slice * 128 + cg;
  const int rbase = w * 8 + half * 4;

  const float* wp2 = W2 + ((size_t)t * TH + rbase) * TD + c;
  float4 pA[4], pB[4];
#pragma unroll
  for (int k = 0; k < 4; ++k) pA[k] = *(const float4*)(wp2 + k * TD);
#pragma unroll
  for (int k = 0; k < 4; ++k) pB[k] = *(const float4*)(wp2 + (32 + k) * TD);

  {  // contiguous stage: hbuf[t] is [8][768] = exactly st's layout
    const float4* src = (const float4*)(hbuf + (size_t)t * TB * TH);
    float4* dst = (float4*)&st[0][0];
#pragma unroll
    for (int i = 0; i < 6; ++i) dst[tid + i * 256] = src[tid + i * 256];
  }
  __syncthreads();

  float acc[8][4];
#pragma unroll
  for (int b = 0; b < 8; ++b)
#pragma unroll
    for (int j = 0; j < 4; ++j) acc[b][j] = 0.f;

  BODY4(pA, rbase);
  BODY4(pB, rbase + 32);
  {
    const float* wp = wp2 + (size_t)64 * TD;
#pragma unroll 2
    for (int g = 2; g < 24; ++g) {
      float4 wv[4];
#pragma unroll
      for (int k = 0; k < 4; ++k) wv[k] = *(const float4*)(wp + k * TD);
      wp += 32 * TD;
      BODY4(wv, rbase + 32 * g);
    }
  }

#pragma unroll
  for (int b = 0; b < 8; ++b)
#pragma unroll
    for (int j = 0; j < 4; ++j)
      acc[b][j] += __shfl_xor(acc[b][j], 32, 64);
  if (lane < 32) {
#pragma unroll
    for (int b = 0; b < 8; ++b)
      *(float4*)&red[w][b][cg] =
          make_float4(acc[b][0], acc[b][1], acc[b][2], acc[b][3]);
  }
  __syncthreads();

  {  // epilogue: bias + residual, coalesced out
    const int b = tid >> 5;
    const int colq = (tid & 31) * 4;
    const int cc = slice * 128 + colq;
    const size_t off = ((size_t)b * TT + t) * TD + cc;
    const float4 bias = *(const float4*)(b2 + (size_t)t * TD + cc);
    const float4 xres = *(const float4*)(x + off);
    float4 o;
    float* po = (float*)&o;
    const float* pb = (const float*)&bias;
    const float* px = (const float*)&xres;
#pragma unroll
    for (int k = 0; k < 4; ++k)
      po[k] = red[0][b][colq + k] + red[1][b][colq + k] +
              red[2][b][colq + k] + red[3][b][colq + k] + pb[k] + px[k];
    *(float4*)(out + off) = o;
  }
}

extern "C" void kernel_launch(void* const* d_in, const int* in_sizes, int n_in,
                              void* d_out, int out_size, void* d_ws, size_t ws_size,
                              hipStream_t stream) {
  const float* x     = (const float*)d_in[0];
  const float* gamma = (const float*)d_in[1];
  const float* beta  = (const float*)d_in[2];
  const float* W1    = (const float*)d_in[3];
  const float* b1    = (const float*)d_in[4];
  const float* W2    = (const float*)d_in[5];
  const float* b2    = (const float*)d_in[6];
  float* out = (float*)d_out;

  float* hbuf = (float*)d_ws;   // [T][B][H] = 3 MB

  ff1_kernel<<<TT * 6, 256, 0, stream>>>(x, gamma, beta, W1, b1, hbuf);
  ff2_kernel<<<TT * 6, 256, 0, stream>>>(hbuf, W2, b2, x, out);
}

// Round 11
// 115.677 us; speedup vs baseline: 1.0216x; 1.0216x over previous
//
#include <hip/hip_runtime.h>
#include <math.h>

#define TB 8      // batch
#define TT 128    // tokens
#define TD 768    // dim
#define TH 768    // hidden
#define LN_EPS 1e-5f

// 4-K-row FMA body: weight rows in WV[0..3] (4 cols/lane) against
// LDS-broadcast activations st[b][ROW..ROW+3].
#define BODY4(WV, ROW)                                                \
  {                                                                   \
    float4 xq[8];                                                     \
    _Pragma("unroll") for (int b = 0; b < 8; ++b)                     \
        xq[b] = *(const float4*)&st[b][(ROW)];                        \
    _Pragma("unroll") for (int k = 0; k < 4; ++k) {                   \
      _Pragma("unroll") for (int b = 0; b < 8; ++b) {                 \
        const float xv = ((const float*)&xq[b])[k];                   \
        acc[b][0] = fmaf(xv, (WV)[k].x, acc[b][0]);                   \
        acc[b][1] = fmaf(xv, (WV)[k].y, acc[b][1]);                   \
        acc[b][2] = fmaf(xv, (WV)[k].z, acc[b][2]);                   \
        acc[b][3] = fmaf(xv, (WV)[k].w, acc[b][3]);                   \
      }                                                               \
    }                                                                 \
  }

// ---------------------------------------------------------------------------
// FF1 with fused LayerNorm. Block = (token t, 128-col slice of H), 256 thr.
// LN: wave w half h handles batch row b = 2w+h (32 lanes over D=768),
// result staged to st[b][d] in LDS. GEMM: half-wave owns a 96-row K-chunk
// (8-way K split); lane owns 4 cols (float4 weight loads, 16 B/lane).
// ---------------------------------------------------------------------------
__global__ __launch_bounds__(256) void ff1_kernel(
    const float* __restrict__ x,      // [B][T][D]
    const float* __restrict__ gamma,  // [T][D]
    const float* __restrict__ beta,   // [T][D]
    const float* __restrict__ W1,     // [T][D][H]
    const float* __restrict__ b1,     // [T][H]
    float* __restrict__ hbuf) {       // [T][B][H]
  __shared__ float st[TB][TD];        // 24 KB normalized activations
  __shared__ float red[4][8][128];    // 16 KB partial sums
  const int tid = threadIdx.x;
  const int w = tid >> 6, lane = tid & 63;
  const int half = lane >> 5, l32 = lane & 31;
  const int t = blockIdx.x / 6, slice = blockIdx.x % 6;
  const int cg = l32 * 4;
  const int c = slice * 128 + cg;
  const int r0 = w * 192 + half * 96;

  {  // ---- fused LN for batch row b = 2w + half
    const int b = w * 2 + half;
    const float* xr = x + ((size_t)b * TT + t) * TD;
    float4 v[6];
    float s = 0.f, ss = 0.f;
#pragma unroll
    for (int i = 0; i < 6; ++i) {
      v[i] = *(const float4*)(xr + i * 128 + l32 * 4);
      s += v[i].x + v[i].y + v[i].z + v[i].w;
      ss += v[i].x * v[i].x + v[i].y * v[i].y + v[i].z * v[i].z +
            v[i].w * v[i].w;
    }
#pragma unroll
    for (int off = 16; off; off >>= 1) {  // reduce within the 32-lane half
      s  += __shfl_xor(s, off, 64);
      ss += __shfl_xor(ss, off, 64);
    }
    const float mu   = s * (1.f / TD);
    const float var  = ss * (1.f / TD) - mu * mu;
    const float rstd = rsqrtf(var + LN_EPS);
#pragma unroll
    for (int i = 0; i < 6; ++i) {
      const int d = i * 128 + l32 * 4;
      const float4 g  = *(const float4*)(gamma + (size_t)t * TD + d);
      const float4 be = *(const float4*)(beta  + (size_t)t * TD + d);
      float4 o;
      o.x = (v[i].x - mu) * rstd * g.x + be.x;
      o.y = (v[i].y - mu) * rstd * g.y + be.y;
      o.z = (v[i].z - mu) * rstd * g.z + be.z;
      o.w = (v[i].w - mu) * rstd * g.w + be.w;
      *(float4*)&st[b][d] = o;
    }
  }
  __syncthreads();

  float acc[8][4];
#pragma unroll
  for (int b = 0; b < 8; ++b)
#pragma unroll
    for (int j = 0; j < 4; ++j) acc[b][j] = 0.f;

  {
    const float* wp = W1 + ((size_t)t * TD + r0) * TH + c;
#pragma unroll 2
    for (int dd = 0; dd < 96; dd += 4) {
      float4 wv[4];
#pragma unroll
      for (int k = 0; k < 4; ++k) wv[k] = *(const float4*)(wp + k * TH);
      wp += 4 * TH;
      BODY4(wv, r0 + dd);
    }
  }

#pragma unroll
  for (int b = 0; b < 8; ++b)
#pragma unroll
    for (int j = 0; j < 4; ++j)
      acc[b][j] += __shfl_xor(acc[b][j], 32, 64);
  if (lane < 32) {
#pragma unroll
    for (int b = 0; b < 8; ++b)
      *(float4*)&red[w][b][cg] =
          make_float4(acc[b][0], acc[b][1], acc[b][2], acc[b][3]);
  }
  __syncthreads();

  {  // epilogue: bias + GELU, thread -> (batch row, 4-col group)
    const int b = tid >> 5;
    const int colq = (tid & 31) * 4;
    const int cc = slice * 128 + colq;
    const float4 bias = *(const float4*)(b1 + (size_t)t * TH + cc);
    float4 o;
    float* po = (float*)&o;
    const float* pb = (const float*)&bias;
#pragma unroll
    for (int k = 0; k < 4; ++k) {
      float vv = red[0][b][colq + k] + red[1][b][colq + k] +
                 red[2][b][colq + k] + red[3][b][colq + k] + pb[k];
      po[k] = 0.5f * vv * (1.f + erff(vv * 0.7071067811865476f));
    }
    *(float4*)(hbuf + ((size_t)t * TB + b) * TH + cc) = o;
  }
}

// ---------------------------------------------------------------------------
// FF2: out = h @ W2 + b2 + x. Same GEMM structure; h staged from [T][B][H]
// with a contiguous copy; epilogue/residual are 512B-contiguous per b.
// ---------------------------------------------------------------------------
__global__ __launch_bounds__(256) void ff2_kernel(
    const float* __restrict__ hbuf, // [T][B][H]
    const float* __restrict__ W2,   // [T][H][D]
    const float* __restrict__ b2,   // [T][D]
    const float* __restrict__ x,    // [B][T][D]
    float* __restrict__ out) {      // [B][T][D]
  __shared__ float st[TB][TH];
  __shared__ float red[4][8][128];
  const int tid = threadIdx.x;
  const int w = tid >> 6, lane = tid & 63;
  const int half = lane >> 5, l32 = lane & 31;
  const int t = blockIdx.x / 6, slice = blockIdx.x % 6;
  const int cg = l32 * 4;
  const int c = slice * 128 + cg;
  const int r0 = w * 192 + half * 96;

  {  // contiguous stage: hbuf[t] is [8][768] = exactly st's layout
    const float4* src = (const float4*)(hbuf + (size_t)t * TB * TH);
    float4* dst = (float4*)&st[0][0];
#pragma unroll
    for (int i = 0; i < 6; ++i) dst[tid + i * 256] = src[tid + i * 256];
  }
  __syncthreads();

  float acc[8][4];
#pragma unroll
  for (int b = 0; b < 8; ++b)
#pragma unroll
    for (int j = 0; j < 4; ++j) acc[b][j] = 0.f;

  {
    const float* wp = W2 + ((size_t)t * TH + r0) * TD + c;
#pragma unroll 2
    for (int dd = 0; dd < 96; dd += 4) {
      float4 wv[4];
#pragma unroll
      for (int k = 0; k < 4; ++k) wv[k] = *(const float4*)(wp + k * TD);
      wp += 4 * TD;
      BODY4(wv, r0 + dd);
    }
  }

#pragma unroll
  for (int b = 0; b < 8; ++b)
#pragma unroll
    for (int j = 0; j < 4; ++j)
      acc[b][j] += __shfl_xor(acc[b][j], 32, 64);
  if (lane < 32) {
#pragma unroll
    for (int b = 0; b < 8; ++b)
      *(float4*)&red[w][b][cg] =
          make_float4(acc[b][0], acc[b][1], acc[b][2], acc[b][3]);
  }
  __syncthreads();

  {  // epilogue: bias + residual, coalesced out
    const int b = tid >> 5;
    const int colq = (tid & 31) * 4;
    const int cc = slice * 128 + colq;
    const size_t off = ((size_t)b * TT + t) * TD + cc;
    const float4 bias = *(const float4*)(b2 + (size_t)t * TD + cc);
    const float4 xres = *(const float4*)(x + off);
    float4 o;
    float* po = (float*)&o;
    const float* pb = (const float*)&bias;
    const float* px = (const float*)&xres;
#pragma unroll
    for (int k = 0; k < 4; ++k)
      po[k] = red[0][b][colq + k] + red[1][b][colq + k] +
              red[2][b][colq + k] + red[3][b][colq + k] + pb[k] + px[k];
    *(float4*)(out + off) = o;
  }
}

extern "C" void kernel_launch(void* const* d_in, const int* in_sizes, int n_in,
                              void* d_out, int out_size, void* d_ws, size_t ws_size,
                              hipStream_t stream) {
  const float* x     = (const float*)d_in[0];
  const float* gamma = (const float*)d_in[1];
  const float* beta  = (const float*)d_in[2];
  const float* W1    = (const float*)d_in[3];
  const float* b1    = (const float*)d_in[4];
  const float* W2    = (const float*)d_in[5];
  const float* b2    = (const float*)d_in[6];
  float* out = (float*)d_out;

  float* hbuf = (float*)d_ws;   // [T][B][H] = 3 MB

  ff1_kernel<<<TT * 6, 256, 0, stream>>>(x, gamma, beta, W1, b1, hbuf);
  ff2_kernel<<<TT * 6, 256, 0, stream>>>(hbuf, W2, b2, x, out);
}